// Round 1
// baseline (6703.082 us; speedup 1.0000x reference)
//
#include <hip/hip_runtime.h>
#include <stdint.h>

// B=256, S=512, ENC=256, DEC=256, ATTN=128, H=48
#define LOG2E 1.4426950408889634f

typedef short v8s __attribute__((ext_vector_type(8)));
typedef float v4f __attribute__((ext_vector_type(4)));

__device__ __forceinline__ uint32_t bf16r(float x){
  uint32_t u = __float_as_uint(x);
  return (u + 0x7fffu + ((u >> 16) & 1u)) >> 16;   // RNE round to bf16
}
__device__ __forceinline__ uint32_t pack2(float lo, float hi){
  return bf16r(lo) | (bf16r(hi) << 16);
}
__device__ __forceinline__ float unlo(uint32_t u){ return __uint_as_float(u << 16); }
__device__ __forceinline__ float unhi(uint32_t u){ return __uint_as_float(u & 0xffff0000u); }

__device__ __forceinline__ float fexp2(float x){ return __builtin_amdgcn_exp2f(x); }
__device__ __forceinline__ float frcp(float x){ return __builtin_amdgcn_rcpf(x); }
__device__ __forceinline__ float ftanh(float x){
  float e = fexp2(x * (2.0f * LOG2E));   // exp(2x)
  return 1.0f - 2.0f * frcp(e + 1.0f);
}
__device__ __forceinline__ float fsig(float x){
  return frcp(1.0f + fexp2(-x * LOG2E));
}
__device__ __forceinline__ float wave_sum(float x){
  #pragma unroll
  for(int o = 32; o; o >>= 1) x += __shfl_xor(x, o, 64);
  return x;
}

// Gate-row interleave: jg = n*64 + dl*4 + gate ; row = gate*256 + n*16 + dl
__device__ __forceinline__ int gate_row(int jg){
  return (jg & 3) * 256 + (jg >> 6) * 16 + ((jg >> 2) & 15);
}

// ---- P1: pack gate weights bf16 (interleaved rows) + WencT split hi/lo bf16 ----
__global__ __launch_bounds__(256) void k_pack(const float* __restrict__ W_ih,
                                              const float* __restrict__ W_hh,
                                              const float* __restrict__ b_ih,
                                              const float* __restrict__ b_hh,
                                              const float* __restrict__ W_enc,
                                              unsigned short* __restrict__ WmT,
                                              float* __restrict__ biasc,
                                              float* __restrict__ w0v,
                                              unsigned short* __restrict__ WencTh,
                                              unsigned short* __restrict__ WencTl){
  int gid = blockIdx.x * 256 + threadIdx.x;   // 98304
  if(gid < 65536){
    int jg = gid >> 6, k8 = gid & 63;
    int row = gate_row(jg);
    int k0 = k8 * 8;
    uint32_t p[4];
    #pragma unroll
    for(int mm = 0; mm < 4; ++mm){
      int ka = k0 + 2 * mm, kb = ka + 1;
      float lo = (ka < 256) ? W_ih[row * 257 + 1 + ka] : W_hh[row * 256 + (ka - 256)];
      float hi = (kb < 256) ? W_ih[row * 257 + 1 + kb] : W_hh[row * 256 + (kb - 256)];
      p[mm] = pack2(lo, hi);
    }
    *(uint4*)&WmT[(size_t)jg * 512 + k0] = make_uint4(p[0], p[1], p[2], p[3]);
    if(k8 == 0){
      biasc[jg] = b_ih[row] + b_hh[row];
      w0v[jg] = W_ih[row * 257];
    }
  } else {
    int g2 = gid - 65536;                    // 32768 = 256k x 128a
    int k = g2 >> 7, a = g2 & 127;
    float x = W_enc[k * 128 + a];
    uint32_t hb = bf16r(x);
    WencTh[a * 256 + k] = (unsigned short)hb;
    float hv = __uint_as_float(hb << 16);
    WencTl[a * 256 + k] = (unsigned short)bf16r(x - hv);
  }
}

// ---- P2: enc_proj via MFMA bf16 with split hi/lo inputs (near-fp32 precision). ----
__global__ __launch_bounds__(256, 2) void k_enc_proj(const float* __restrict__ enc,
                                                     const unsigned short* __restrict__ WencTh,
                                                     const unsigned short* __restrict__ WencTl,
                                                     unsigned short* __restrict__ ep,
                                                     uint32_t* __restrict__ encb){
  __shared__ unsigned short Ash[128][48];  // [s-local][k-chunk] hi
  __shared__ unsigned short Asl[128][48];  // lo
  __shared__ unsigned short Wth[128][48];  // [a][k-chunk] hi
  __shared__ unsigned short Wtl[128][48];  // lo
  const int tid = threadIdx.x;
  const int b = blockIdx.x >> 2, mt = blockIdx.x & 3;
  const int lane = tid & 63, w = tid >> 6;
  const int rr = lane & 15, quad = lane >> 4;

  v4f acc[2][8];
  #pragma unroll
  for(int g = 0; g < 2; ++g)
    #pragma unroll
    for(int nt = 0; nt < 8; ++nt) acc[g][nt] = (v4f){0.f, 0.f, 0.f, 0.f};

  const float* encBase = enc + ((size_t)(b * 512 + mt * 128)) * 256;
  uint32_t* encbBase = encb + ((size_t)(b * 512 + mt * 128)) * 128;

  for(int kt = 0; kt < 8; ++kt){
    __syncthreads();
    #pragma unroll
    for(int i = 0; i < 4; ++i){
      int flat = i * 256 + tid;              // 1024 = 128 rows x 8 float4
      int row = flat >> 3, c4 = flat & 7;
      float4 f = *(const float4*)(encBase + (size_t)row * 256 + kt * 32 + c4 * 4);
      uint32_t hx = bf16r(f.x), hy = bf16r(f.y), hz = bf16r(f.z), hw = bf16r(f.w);
      uint2 hp = make_uint2(hx | (hy << 16), hz | (hw << 16));
      float lx = f.x - __uint_as_float(hx << 16);
      float ly = f.y - __uint_as_float(hy << 16);
      float lz = f.z - __uint_as_float(hz << 16);
      float lw = f.w - __uint_as_float(hw << 16);
      uint2 lp = make_uint2(pack2(lx, ly), pack2(lz, lw));
      *(uint2*)&Ash[row][c4 * 4] = hp;
      *(uint2*)&Asl[row][c4 * 4] = lp;
      *(uint2*)&encbBase[(size_t)row * 128 + kt * 16 + c4 * 2] = hp;
    }
    #pragma unroll
    for(int i = 0; i < 2; ++i){
      int flat = i * 256 + tid;              // 512 = 128 a x 4 uint4
      int a = flat >> 2, q4 = flat & 3;
      *(uint4*)&Wth[a][q4 * 8] = *(const uint4*)(WencTh + (size_t)a * 256 + kt * 32 + q4 * 8);
      *(uint4*)&Wtl[a][q4 * 8] = *(const uint4*)(WencTl + (size_t)a * 256 + kt * 32 + q4 * 8);
    }
    __syncthreads();
    #pragma unroll
    for(int g = 0; g < 2; ++g){
      v8s ah = *(const v8s*)&Ash[32 * w + 16 * g + rr][quad * 8];
      v8s al = *(const v8s*)&Asl[32 * w + 16 * g + rr][quad * 8];
      #pragma unroll
      for(int nt = 0; nt < 8; ++nt){
        v8s bh = *(const v8s*)&Wth[nt * 16 + rr][quad * 8];
        v8s bl = *(const v8s*)&Wtl[nt * 16 + rr][quad * 8];
        acc[g][nt] = __builtin_amdgcn_mfma_f32_16x16x32_bf16(ah, bh, acc[g][nt], 0, 0, 0);
        acc[g][nt] = __builtin_amdgcn_mfma_f32_16x16x32_bf16(al, bh, acc[g][nt], 0, 0, 0);
        acc[g][nt] = __builtin_amdgcn_mfma_f32_16x16x32_bf16(ah, bl, acc[g][nt], 0, 0, 0);
      }
    }
  }
  #pragma unroll
  for(int g = 0; g < 2; ++g){
    int s0 = 128 * mt + 32 * w + 16 * g + quad * 4;
    #pragma unroll
    for(int nt = 0; nt < 8; ++nt){
      int a = nt * 16 + rr;
      uint2 pp = make_uint2(pack2(acc[g][nt][0], acc[g][nt][1]),
                            pack2(acc[g][nt][2], acc[g][nt][3]));
      *(uint2*)&ep[((size_t)b * 128 + a) * 512 + s0] = pp;
    }
  }
}

// ---- Fused sequential decoder: grid 256 (1 block = 1 batch), 512 threads,
// all 48 timesteps inside; zero inter-block communication, zero extra launches.
// Gates GEMV via MFMA: A = x broadcast into all 16 m-rows (rows identical, any
// row of D is the answer); B-fragments stream from L2-resident WmT. The h-half
// (kt 8..15) issues first so its L2 stream overlaps the tanh-heavy scores phase.
__global__ __launch_bounds__(512) void k_steps(
    const uint32_t* __restrict__ encb, const unsigned short* __restrict__ ep,
    const unsigned short* __restrict__ WmT, const float* __restrict__ biasc,
    const float* __restrict__ w0v, const float* __restrict__ Wdec,
    const float* __restrict__ Wout, const float* __restrict__ h0,
    const float* __restrict__ c0, const float* __restrict__ v,
    const float* __restrict__ b_out, float* __restrict__ out)
{
  __shared__ float dpf[128];                 // dec_proj of current h
  __shared__ float vl[128];
  __shared__ float scp[512][9];              // [s][q] score partials
  __shared__ float attn_l[512];
  __shared__ float ctxp[16][256];            // [g][e] context partials
  __shared__ float red2[8];
  __shared__ float red4[4];
  __shared__ float hf[256];                  // h (f32) for dp GEMV
  __shared__ float dppart[4][128];
  __shared__ __align__(16) float gact[1024]; // gates pre-activation accum
  __shared__ __align__(16) unsigned short xb[512]; // [ctx bf16 | h bf16]
  __shared__ float predv;

  const int tid = threadIdx.x, b = blockIdx.x;
  const int lane = tid & 63, wid = tid >> 6;
  const int quad = lane >> 4, rr = lane & 15;

  // ---- init state ----
  float c_reg = 0.f;
  if(tid < 256){
    float hv = h0[b * 256 + tid];
    hf[tid] = hv;
    xb[256 + tid] = (unsigned short)bf16r(hv);
    c_reg = c0[b * 256 + tid];
  }
  if(tid < 128) vl[tid] = v[tid];
  if(tid == 0) predv = 0.f;
  __syncthreads();
  // dpf = h0 @ Wdec (f32)
  {
    int a = tid & 127, p = tid >> 7;
    float s = 0.f;
    const float* wd = Wdec + (size_t)(p * 64) * 128 + a;
    #pragma unroll 8
    for(int d = 0; d < 64; ++d) s += hf[p * 64 + d] * wd[(size_t)d * 128];
    dppart[p][a] = s;
  }
  __syncthreads();
  if(tid < 128) dpf[tid] = dppart[0][tid] + dppart[1][tid] + dppart[2][tid] + dppart[3][tid];
  __syncthreads();

  const uint4* ep4 = (const uint4*)(ep + (size_t)b * 65536);
  const uint4* eb  = (const uint4*)(encb + (size_t)b * 65536);
  // wave wid owns j-tiles wid*8..wid*8+7 ; B-row for tile ti = jg (wid*8+ti)*16+rr
  const unsigned short* wb = WmT + ((size_t)(wid * 128) + rr) * 512 + quad * 8;

  #pragma unroll 1
  for(int t = 0; t < 48; ++t){
    // prefetch ep rows for scores (in flight during h-half GEMM)
    uint4 u[16];
    #pragma unroll
    for(int i = 0; i < 16; ++i) u[i] = ep4[(wid * 16 + i) * 64 + lane];

    // ---- gates GEMV, h half (kt=8..15): x_h known from prev step ----
    v4f acc[8];
    #pragma unroll
    for(int ti = 0; ti < 8; ++ti) acc[ti] = (v4f){0.f, 0.f, 0.f, 0.f};
    #pragma unroll
    for(int kt = 8; kt < 16; ++kt){
      v8s av = *(const v8s*)&xb[kt * 32 + quad * 8];   // broadcast x into all m-rows
      #pragma unroll
      for(int ti = 0; ti < 8; ++ti){
        v8s bv = *(const v8s*)(wb + (size_t)ti * 8192 + kt * 32);
        acc[ti] = __builtin_amdgcn_mfma_f32_16x16x32_bf16(av, bv, acc[ti], 0, 0, 0);
      }
    }

    // ---- scores: thread (sb=lane, q=wid): s = lane*8+j, a in [16q,16q+16) ----
    {
      float sc[8];
      #pragma unroll
      for(int j = 0; j < 8; ++j) sc[j] = 0.f;
      #pragma unroll
      for(int i = 0; i < 16; ++i){
        int a = wid * 16 + i;
        float dd = dpf[a], vv = vl[a];
        sc[0] += vv * ftanh(unlo(u[i].x) + dd);
        sc[1] += vv * ftanh(unhi(u[i].x) + dd);
        sc[2] += vv * ftanh(unlo(u[i].y) + dd);
        sc[3] += vv * ftanh(unhi(u[i].y) + dd);
        sc[4] += vv * ftanh(unlo(u[i].z) + dd);
        sc[5] += vv * ftanh(unhi(u[i].z) + dd);
        sc[6] += vv * ftanh(unlo(u[i].w) + dd);
        sc[7] += vv * ftanh(unhi(u[i].w) + dd);
      }
      #pragma unroll
      for(int j = 0; j < 8; ++j) scp[lane * 8 + j][wid] = sc[j];
    }
    __syncthreads();

    // ---- softmax over S (max-free: |score| <= ||v||_1 ~ 5) ----
    float wexp;
    {
      float s = 0.f;
      #pragma unroll
      for(int q = 0; q < 8; ++q) s += scp[tid][q];
      wexp = fexp2(s * LOG2E);
      float sw = wave_sum(wexp);
      if(lane == 0) red2[wid] = sw;
    }
    __syncthreads();
    {
      float L = red2[0];
      #pragma unroll
      for(int i = 1; i < 8; ++i) L += red2[i];
      float aw = wexp * frcp(L);
      attn_l[tid] = aw;
      out[12288 + (size_t)b * 24576 + t * 512 + tid] = aw;
    }
    __syncthreads();

    // ---- context: thread (e4=tid&31, g=tid>>5): 8 e-values, s in [32g,32g+32) ----
    {
      int e4 = tid & 31, g = tid >> 5;
      float a8[8] = {0.f, 0.f, 0.f, 0.f, 0.f, 0.f, 0.f, 0.f};
      #pragma unroll 8
      for(int i = 0; i < 32; ++i){
        int s = g * 32 + i;
        float at = attn_l[s];
        uint4 uu = eb[s * 32 + e4];
        a8[0] += at * unlo(uu.x); a8[1] += at * unhi(uu.x);
        a8[2] += at * unlo(uu.y); a8[3] += at * unhi(uu.y);
        a8[4] += at * unlo(uu.z); a8[5] += at * unhi(uu.z);
        a8[6] += at * unlo(uu.w); a8[7] += at * unhi(uu.w);
      }
      #pragma unroll
      for(int j = 0; j < 8; ++j) ctxp[g][e4 * 8 + j] = a8[j];
    }
    __syncthreads();
    if(tid < 256){
      float s = 0.f;
      #pragma unroll
      for(int g = 0; g < 16; ++g) s += ctxp[g][tid];
      xb[tid] = (unsigned short)bf16r(s);
    }
    __syncthreads();

    // ---- gates GEMV, ctx half (kt=0..7) ----
    #pragma unroll
    for(int kt = 0; kt < 8; ++kt){
      v8s av = *(const v8s*)&xb[kt * 32 + quad * 8];
      #pragma unroll
      for(int ti = 0; ti < 8; ++ti){
        v8s bv = *(const v8s*)(wb + (size_t)ti * 8192 + kt * 32);
        acc[ti] = __builtin_amdgcn_mfma_f32_16x16x32_bf16(av, bv, acc[ti], 0, 0, 0);
      }
    }
    if(quad == 0){
      #pragma unroll
      for(int ti = 0; ti < 8; ++ti) gact[(wid * 8 + ti) * 16 + rr] = acc[ti][0];
    }
    __syncthreads();

    // ---- pointwise LSTM (thread = d) ----
    if(tid < 256){
      int jgb = (tid >> 4) * 64 + (tid & 15) * 4;   // jg of gate 0 for this d
      float4 g4  = *(const float4*)&gact[jgb];
      float4 bi  = *(const float4*)&biasc[jgb];
      float4 w04 = *(const float4*)&w0v[jgb];
      float pv = predv;
      float gi = fsig (g4.x + bi.x + pv * w04.x);
      float gf = fsig (g4.y + bi.y + pv * w04.y);
      float gg = ftanh(g4.z + bi.z + pv * w04.z);
      float go = fsig (g4.w + bi.w + pv * w04.w);
      float cn = gf * c_reg + gi * gg;
      c_reg = cn;
      float hn = go * ftanh(cn);
      hf[tid] = hn;
      xb[256 + tid] = (unsigned short)bf16r(hn);
      float pp = hn * Wout[tid];
      #pragma unroll
      for(int o = 32; o; o >>= 1) pp += __shfl_xor(pp, o, 64);
      if(lane == 0) red4[wid] = pp;
    }
    __syncthreads();
    if(tid == 0){
      float pr = red4[0] + red4[1] + red4[2] + red4[3] + b_out[0];
      predv = pr;
      out[b * 48 + t] = pr;
    }
    // ---- dpf = h_new @ Wdec (f32) ----
    {
      int a = tid & 127, p = tid >> 7;
      float s = 0.f;
      const float* wd = Wdec + (size_t)(p * 64) * 128 + a;
      #pragma unroll 8
      for(int d = 0; d < 64; ++d) s += hf[p * 64 + d] * wd[(size_t)d * 128];
      dppart[p][a] = s;
    }
    __syncthreads();
    if(tid < 128) dpf[tid] = dppart[0][tid] + dppart[1][tid] + dppart[2][tid] + dppart[3][tid];
    __syncthreads();
  }
}

extern "C" void kernel_launch(void* const* d_in, const int* in_sizes, int n_in,
                              void* d_out, int out_size, void* d_ws, size_t ws_size,
                              hipStream_t stream) {
  (void)in_sizes; (void)n_in; (void)out_size; (void)ws_size;
  const float* enc  = (const float*)d_in[0];
  const float* h0   = (const float*)d_in[1];
  const float* c0   = (const float*)d_in[2];
  const float* Wenc = (const float*)d_in[3];
  const float* Wdec = (const float*)d_in[4];
  const float* v    = (const float*)d_in[5];
  const float* Wih  = (const float*)d_in[6];
  const float* Whh  = (const float*)d_in[7];
  const float* bih  = (const float*)d_in[8];
  const float* bhh  = (const float*)d_in[9];
  const float* Wout = (const float*)d_in[10];
  const float* bout = (const float*)d_in[11];
  float* out = (float*)d_out;
  uint8_t* p = (uint8_t*)d_ws;

  uint32_t* encb = (uint32_t*)p;            p += 67108864ull;  // [256][512][128] u32 pairs
  unsigned short* ep = (unsigned short*)p;  p += 33554432ull;  // [256][128][512] bf16
  unsigned short* WmT = (unsigned short*)p; p += 1048576ull;   // [1024][512] bf16
  float* biasc  = (float*)p;                p += 4096ull;
  float* w0v    = (float*)p;                p += 4096ull;
  unsigned short* WencTh = (unsigned short*)p; p += 131072ull; // [128][256] bf16 hi
  unsigned short* WencTl = (unsigned short*)p; p += 131072ull; // [128][256] bf16 lo

  k_pack<<<dim3(384), dim3(256), 0, stream>>>(Wih, Whh, bih, bhh, Wenc, WmT, biasc, w0v,
                                              WencTh, WencTl);
  k_enc_proj<<<dim3(1024), dim3(256), 0, stream>>>(enc, WencTh, WencTl, ep, encb);
  k_steps<<<dim3(256), dim3(512), 0, stream>>>(encb, ep, WmT, biasc, w0v, Wdec, Wout,
                                               h0, c0, v, bout, out);
}

// Round 2
// 1416.214 us; speedup vs baseline: 4.7331x; 4.7331x over previous
//
#include <hip/hip_runtime.h>
#include <stdint.h>

// B=256, S=512, ENC=256, DEC=256, ATTN=128, H=48
#define LOG2E 1.4426950408889634f
#define SCOPE __HIP_MEMORY_SCOPE_AGENT

typedef short v8s __attribute__((ext_vector_type(8)));
typedef float v4f __attribute__((ext_vector_type(4)));

__device__ __forceinline__ uint32_t bf16r(float x){
  uint32_t u = __float_as_uint(x);
  return (u + 0x7fffu + ((u >> 16) & 1u)) >> 16;   // RNE round to bf16
}
__device__ __forceinline__ uint32_t pack2(float lo, float hi){
  return bf16r(lo) | (bf16r(hi) << 16);
}
__device__ __forceinline__ float unlo(uint32_t u){ return __uint_as_float(u << 16); }
__device__ __forceinline__ float unhi(uint32_t u){ return __uint_as_float(u & 0xffff0000u); }

__device__ __forceinline__ float fexp2(float x){ return __builtin_amdgcn_exp2f(x); }
__device__ __forceinline__ float frcp(float x){ return __builtin_amdgcn_rcpf(x); }
__device__ __forceinline__ float ftanh(float x){
  float e = fexp2(x * (2.0f * LOG2E));   // exp(2x)
  return 1.0f - 2.0f * frcp(e + 1.0f);
}
__device__ __forceinline__ float fsig(float x){
  return frcp(1.0f + fexp2(-x * LOG2E));
}
__device__ __forceinline__ float wave_sum(float x){
  #pragma unroll
  for(int o = 32; o; o >>= 1) x += __shfl_xor(x, o, 64);
  return x;
}

// Coherent (agent-scope, L3-serialized) access helpers — all cross-block data
// goes through these so no cache-wide wbl2/inv fences are ever needed.
__device__ __forceinline__ unsigned flag_ld(const unsigned* p){
  return __hip_atomic_load(p, __ATOMIC_RELAXED, SCOPE);
}
__device__ __forceinline__ void flag_st(unsigned* p, unsigned v){
  __hip_atomic_store(p, v, __ATOMIC_RELAXED, SCOPE);
}
__device__ __forceinline__ float ldf_c(const float* p){
  return __hip_atomic_load(p, __ATOMIC_RELAXED, SCOPE);
}
__device__ __forceinline__ void stf_c(float* p, float v){
  __hip_atomic_store(p, v, __ATOMIC_RELAXED, SCOPE);
}
__device__ __forceinline__ uint64_t ld64_c(const uint64_t* p){
  return __hip_atomic_load(p, __ATOMIC_RELAXED, SCOPE);
}
__device__ __forceinline__ void st64_c(uint64_t* p, uint64_t v){
  __hip_atomic_store(p, v, __ATOMIC_RELAXED, SCOPE);
}
__device__ __forceinline__ void st32_c(uint32_t* p, uint32_t v){
  __hip_atomic_store(p, v, __ATOMIC_RELAXED, SCOPE);
}
__device__ __forceinline__ void st16_c(unsigned short* p, unsigned short v){
  __hip_atomic_store(p, v, __ATOMIC_RELAXED, SCOPE);
}

// Gate-row interleave: jg = n*64 + dl*4 + gate ; row = gate*256 + n*16 + dl
__device__ __forceinline__ int gate_row(int jg){
  return (jg & 3) * 256 + (jg >> 6) * 16 + ((jg >> 2) & 15);
}

// ---- P1: pack gate weights bf16 (interleaved rows) + WencT split hi/lo bf16 ----
__global__ __launch_bounds__(256) void k_pack(const float* __restrict__ W_ih,
                                              const float* __restrict__ W_hh,
                                              const float* __restrict__ b_ih,
                                              const float* __restrict__ b_hh,
                                              const float* __restrict__ W_enc,
                                              unsigned short* __restrict__ WmT,
                                              float* __restrict__ biasc,
                                              float* __restrict__ w0v,
                                              unsigned short* __restrict__ WencTh,
                                              unsigned short* __restrict__ WencTl){
  int gid = blockIdx.x * 256 + threadIdx.x;   // 98304
  if(gid < 65536){
    int jg = gid >> 6, k8 = gid & 63;
    int row = gate_row(jg);
    int k0 = k8 * 8;
    uint32_t p[4];
    #pragma unroll
    for(int mm = 0; mm < 4; ++mm){
      int ka = k0 + 2 * mm, kb = ka + 1;
      float lo = (ka < 256) ? W_ih[row * 257 + 1 + ka] : W_hh[row * 256 + (ka - 256)];
      float hi = (kb < 256) ? W_ih[row * 257 + 1 + kb] : W_hh[row * 256 + (kb - 256)];
      p[mm] = pack2(lo, hi);
    }
    *(uint4*)&WmT[(size_t)jg * 512 + k0] = make_uint4(p[0], p[1], p[2], p[3]);
    if(k8 == 0){
      biasc[jg] = b_ih[row] + b_hh[row];
      w0v[jg] = W_ih[row * 257];
    }
  } else {
    int g2 = gid - 65536;                    // 32768 = 256k x 128a
    int k = g2 >> 7, a = g2 & 127;
    float x = W_enc[k * 128 + a];
    uint32_t hb = bf16r(x);
    WencTh[a * 256 + k] = (unsigned short)hb;
    float hv = __uint_as_float(hb << 16);
    WencTl[a * 256 + k] = (unsigned short)bf16r(x - hv);
  }
}

// ---- P2: enc_proj via MFMA bf16 with split hi/lo inputs (near-fp32 precision). ----
__global__ __launch_bounds__(256, 2) void k_enc_proj(const float* __restrict__ enc,
                                                     const unsigned short* __restrict__ WencTh,
                                                     const unsigned short* __restrict__ WencTl,
                                                     unsigned short* __restrict__ ep,
                                                     uint32_t* __restrict__ encb){
  __shared__ unsigned short Ash[128][48];  // [s-local][k-chunk] hi
  __shared__ unsigned short Asl[128][48];  // lo
  __shared__ unsigned short Wth[128][48];  // [a][k-chunk] hi
  __shared__ unsigned short Wtl[128][48];  // lo
  const int tid = threadIdx.x;
  const int b = blockIdx.x >> 2, mt = blockIdx.x & 3;
  const int lane = tid & 63, w = tid >> 6;
  const int rr = lane & 15, quad = lane >> 4;

  v4f acc[2][8];
  #pragma unroll
  for(int g = 0; g < 2; ++g)
    #pragma unroll
    for(int nt = 0; nt < 8; ++nt) acc[g][nt] = (v4f){0.f, 0.f, 0.f, 0.f};

  const float* encBase = enc + ((size_t)(b * 512 + mt * 128)) * 256;
  uint32_t* encbBase = encb + ((size_t)(b * 512 + mt * 128)) * 128;

  for(int kt = 0; kt < 8; ++kt){
    __syncthreads();
    #pragma unroll
    for(int i = 0; i < 4; ++i){
      int flat = i * 256 + tid;              // 1024 = 128 rows x 8 float4
      int row = flat >> 3, c4 = flat & 7;
      float4 f = *(const float4*)(encBase + (size_t)row * 256 + kt * 32 + c4 * 4);
      uint32_t hx = bf16r(f.x), hy = bf16r(f.y), hz = bf16r(f.z), hw = bf16r(f.w);
      uint2 hp = make_uint2(hx | (hy << 16), hz | (hw << 16));
      float lx = f.x - __uint_as_float(hx << 16);
      float ly = f.y - __uint_as_float(hy << 16);
      float lz = f.z - __uint_as_float(hz << 16);
      float lw = f.w - __uint_as_float(hw << 16);
      uint2 lp = make_uint2(pack2(lx, ly), pack2(lz, lw));
      *(uint2*)&Ash[row][c4 * 4] = hp;
      *(uint2*)&Asl[row][c4 * 4] = lp;
      *(uint2*)&encbBase[(size_t)row * 128 + kt * 16 + c4 * 2] = hp;
    }
    #pragma unroll
    for(int i = 0; i < 2; ++i){
      int flat = i * 256 + tid;              // 512 = 128 a x 4 uint4
      int a = flat >> 2, q4 = flat & 3;
      *(uint4*)&Wth[a][q4 * 8] = *(const uint4*)(WencTh + (size_t)a * 256 + kt * 32 + q4 * 8);
      *(uint4*)&Wtl[a][q4 * 8] = *(const uint4*)(WencTl + (size_t)a * 256 + kt * 32 + q4 * 8);
    }
    __syncthreads();
    #pragma unroll
    for(int g = 0; g < 2; ++g){
      v8s ah = *(const v8s*)&Ash[32 * w + 16 * g + rr][quad * 8];
      v8s al = *(const v8s*)&Asl[32 * w + 16 * g + rr][quad * 8];
      #pragma unroll
      for(int nt = 0; nt < 8; ++nt){
        v8s bh = *(const v8s*)&Wth[nt * 16 + rr][quad * 8];
        v8s bl = *(const v8s*)&Wtl[nt * 16 + rr][quad * 8];
        acc[g][nt] = __builtin_amdgcn_mfma_f32_16x16x32_bf16(ah, bh, acc[g][nt], 0, 0, 0);
        acc[g][nt] = __builtin_amdgcn_mfma_f32_16x16x32_bf16(al, bh, acc[g][nt], 0, 0, 0);
        acc[g][nt] = __builtin_amdgcn_mfma_f32_16x16x32_bf16(ah, bl, acc[g][nt], 0, 0, 0);
      }
    }
  }
  #pragma unroll
  for(int g = 0; g < 2; ++g){
    int s0 = 128 * mt + 32 * w + 16 * g + quad * 4;
    #pragma unroll
    for(int nt = 0; nt < 8; ++nt){
      int a = nt * 16 + rr;
      uint2 pp = make_uint2(pack2(acc[g][nt][0], acc[g][nt][1]),
                            pack2(acc[g][nt][2], acc[g][nt][3]));
      *(uint2*)&ep[((size_t)b * 128 + a) * 512 + s0] = pp;
    }
  }
}

// ---- P3: reset flags (ws persists across harness iterations) ----
__global__ __launch_bounds__(512) void k_zero(unsigned* __restrict__ fl){
  fl[threadIdx.x] = 0u;   // flagA[256] | flagB[256]
}

// ---- Persistent fused decoder: grid 256 (1 block = 1 batch = 1 CU), 512 thr.
// Per step, block b: (A) attention for batch b [round-0 k_attn math], then
// (B) gates slice (m=b>>4, n=b&15) for its 16-batch m-group [round-0 k_gates
// MFMA math], with WT/WdecL/bias staged in LDS ONCE. Cross-block handoff via
// per-generation flags + agent-scope (L3-coherent) relaxed atomics. All
// communication stays within the 16-block m-group; no grid barriers.
__global__ __launch_bounds__(512, 2) void k_steps(
    const uint32_t* __restrict__ encb, const unsigned short* __restrict__ ep,
    const unsigned short* __restrict__ WmT, const float* __restrict__ biasc,
    const float* __restrict__ w0v, const float* __restrict__ Wdec,
    const float* __restrict__ Wout, const float* __restrict__ h0,
    const float* __restrict__ c0, const float* __restrict__ v,
    const float* __restrict__ b_out, unsigned* __restrict__ flagA,
    unsigned* __restrict__ flagB, float* __restrict__ predf,
    float* __restrict__ dpp, float* __restrict__ predp,
    unsigned short* __restrict__ xcat2, float* __restrict__ out)
{
  __shared__ __align__(16) unsigned short WT[64][520];  // gate weights (persistent)
  __shared__ __align__(16) unsigned short AT[16][520];  // x rows of m-group
  __shared__ float WdecL[16][128];                      // Wdec slice (persistent)
  __shared__ float gact[64][20];
  __shared__ float hl[16][17];
  __shared__ float dpf[128];
  __shared__ float vl[128];
  __shared__ float scp[512][9];
  __shared__ float attn_l[512];
  __shared__ float ctxp[16][256];
  __shared__ float ctxf[256];
  __shared__ float red2[8];
  __shared__ float hf[256];
  __shared__ float dppart[4][128];
  __shared__ float biasL[64], w0L[64], WoutL[16], predfL[16];
  __shared__ float sB;

  const int tid = threadIdx.x, b = blockIdx.x;
  const int lane = tid & 63, wid = tid >> 6;
  const int m16 = (b >> 4) << 4;     // first batch of our m-group
  const int n = b & 15;              // our gates n-slice

  // ---- one-time staging (weights live in LDS for all 48 steps) ----
  {
    const uint4* src = (const uint4*)(WmT + (size_t)(n * 64) * 512);
    #pragma unroll
    for(int i = 0; i < 8; ++i){
      int flat = i * 512 + tid;            // 4096 = 64 rows x 64 uint4
      int r = flat >> 6, q = flat & 63;
      *(uint4*)&WT[r][q * 8] = src[r * 64 + q];
    }
    const float4* wsrc = (const float4*)(Wdec + (size_t)(n * 16) * 128);
    int r2 = tid >> 5, q2 = tid & 31;      // 512 = 16 rows x 32 float4
    *(float4*)&WdecL[r2][q2 * 4] = wsrc[r2 * 32 + q2];
    if(tid < 64){ biasL[tid] = biasc[n * 64 + tid]; w0L[tid] = w0v[n * 64 + tid]; }
    if(tid < 16) WoutL[tid] = Wout[n * 16 + tid];
    if(tid < 128) vl[tid] = v[tid];
    if(tid == 0){ sB = b_out[0]; stf_c(&predf[b], 0.f); }
  }
  // ---- init state: c in registers, h0 -> xcat buffer 0 (coherent) ----
  float c_reg = 0.f;
  if(tid < 256){
    int bl = tid >> 4, dl = tid & 15;
    c_reg = c0[(size_t)(m16 + bl) * 256 + n * 16 + dl];
    float hv = h0[(size_t)b * 256 + tid];
    hf[tid] = hv;
    st16_c(&xcat2[(size_t)b * 512 + 256 + tid], (unsigned short)bf16r(hv));
  }
  __syncthreads();
  // dpf(t=0) = h0 @ Wdec (f32)
  {
    int a = tid & 127, p = tid >> 7;
    float s = 0.f;
    const float* wd = Wdec + (size_t)(p * 64) * 128 + a;
    #pragma unroll 8
    for(int d = 0; d < 64; ++d) s += hf[p * 64 + d] * wd[(size_t)d * 128];
    dppart[p][a] = s;
  }
  __syncthreads();
  if(tid < 128) dpf[tid] = dppart[0][tid] + dppart[1][tid] + dppart[2][tid] + dppart[3][tid];
  __syncthreads();

  const uint4* ep4 = (const uint4*)(ep + (size_t)b * 65536);
  const uint4* eb  = (const uint4*)(encb + (size_t)b * 65536);

  #pragma unroll 1
  for(int t = 0; t < 48; ++t){
    unsigned short* xcatP = xcat2 + (size_t)(t & 1) * 131072;        // gates input x_t
    unsigned short* xcatN = xcat2 + (size_t)((t + 1) & 1) * 131072;  // h_{t+1} dest

    // ---- A: wait gates(t-1) of our m-group; fold dpp/predp partials ----
    if(t > 0){
      if(tid < 16){
        unsigned want = (unsigned)t;
        while(flag_ld(&flagB[m16 + tid]) < want) __builtin_amdgcn_s_sleep(1);
      }
      __syncthreads();
      if(tid < 128){
        float s = 0.f;
        #pragma unroll
        for(int nn = 0; nn < 16; ++nn) s += ldf_c(&dpp[((size_t)b * 16 + nn) * 128 + tid]);
        dpf[tid] = s;
      } else if(tid == 128){
        float pf = 0.f;
        #pragma unroll
        for(int nn = 0; nn < 16; ++nn) pf += ldf_c(&predp[nn * 256 + b]);
        pf += sB;
        out[b * 48 + (t - 1)] = pf;
        stf_c(&predf[b], pf);
      }
      __syncthreads();
    }

    // ---- scores: thread (sb=lane, q=wid): s = lane*8+j, a in [16q,16q+16) ----
    {
      uint4 u[16];
      #pragma unroll
      for(int i = 0; i < 16; ++i) u[i] = ep4[(wid * 16 + i) * 64 + lane];
      float sc[8];
      #pragma unroll
      for(int j = 0; j < 8; ++j) sc[j] = 0.f;
      #pragma unroll
      for(int i = 0; i < 16; ++i){
        int a = wid * 16 + i;
        float dd = dpf[a], vv = vl[a];
        sc[0] += vv * ftanh(unlo(u[i].x) + dd);
        sc[1] += vv * ftanh(unhi(u[i].x) + dd);
        sc[2] += vv * ftanh(unlo(u[i].y) + dd);
        sc[3] += vv * ftanh(unhi(u[i].y) + dd);
        sc[4] += vv * ftanh(unlo(u[i].z) + dd);
        sc[5] += vv * ftanh(unhi(u[i].z) + dd);
        sc[6] += vv * ftanh(unlo(u[i].w) + dd);
        sc[7] += vv * ftanh(unhi(u[i].w) + dd);
      }
      #pragma unroll
      for(int j = 0; j < 8; ++j) scp[lane * 8 + j][wid] = sc[j];
    }
    __syncthreads();

    // ---- softmax over S (max-free: |score| <= ||v||_1 ~ 5) ----
    float wexp;
    {
      float s = 0.f;
      #pragma unroll
      for(int q = 0; q < 8; ++q) s += scp[tid][q];
      wexp = fexp2(s * LOG2E);
      float sw = wave_sum(wexp);
      if(lane == 0) red2[wid] = sw;
    }
    __syncthreads();
    {
      float L = red2[0];
      #pragma unroll
      for(int i = 1; i < 8; ++i) L += red2[i];
      float aw = wexp * frcp(L);
      attn_l[tid] = aw;
      out[12288 + (size_t)b * 24576 + t * 512 + tid] = aw;
    }
    __syncthreads();

    // ---- context: thread (e4=tid&31, g=tid>>5): 8 e-values, s in [32g,32g+32) ----
    {
      int e4 = tid & 31, g = tid >> 5;
      float a8[8] = {0.f, 0.f, 0.f, 0.f, 0.f, 0.f, 0.f, 0.f};
      #pragma unroll 8
      for(int i = 0; i < 32; ++i){
        int s = g * 32 + i;
        float at = attn_l[s];
        uint4 uu = eb[s * 32 + e4];
        a8[0] += at * unlo(uu.x); a8[1] += at * unhi(uu.x);
        a8[2] += at * unlo(uu.y); a8[3] += at * unhi(uu.y);
        a8[4] += at * unlo(uu.z); a8[5] += at * unhi(uu.z);
        a8[6] += at * unlo(uu.w); a8[7] += at * unhi(uu.w);
      }
      #pragma unroll
      for(int j = 0; j < 8; ++j) ctxp[g][e4 * 8 + j] = a8[j];
    }
    __syncthreads();
    if(tid < 256){
      float s = 0.f;
      #pragma unroll
      for(int g = 0; g < 16; ++g) s += ctxp[g][tid];
      ctxf[tid] = s;
    }
    __syncthreads();
    if(tid < 128)
      st32_c((uint32_t*)&xcatP[(size_t)b * 512 + 2 * tid],
             pack2(ctxf[2 * tid], ctxf[2 * tid + 1]));
    __syncthreads();                 // drains vmcnt: ctx stores acked at L3
    if(tid == 0) flag_st(&flagA[b], (unsigned)(t + 1));

    // ---- B: wait attn(t) of all 16 batches; gates slice n ----
    if(tid < 16){
      unsigned want = (unsigned)(t + 1);
      while(flag_ld(&flagA[m16 + tid]) < want) __builtin_amdgcn_s_sleep(1);
    }
    __syncthreads();
    {
      const uint64_t* asrc = (const uint64_t*)(xcatP + (size_t)m16 * 512);
      #pragma unroll
      for(int i = 0; i < 4; ++i){
        int flat = i * 512 + tid;          // 2048 = 16 rows x 128 u64
        int r = flat >> 7, q = flat & 127;
        *(uint64_t*)&AT[r][q * 4] = ld64_c(asrc + (size_t)r * 128 + q);
      }
      if(tid < 16) predfL[tid] = ldf_c(&predf[m16 + tid]);
    }
    __syncthreads();
    if(tid < 256){
      const int quad = (tid & 63) >> 4, rr = tid & 15;
      const int jl = (tid >> 6) * 16 + rr;
      v4f acc = {0.f, 0.f, 0.f, 0.f};
      #pragma unroll
      for(int kt = 0; kt < 16; ++kt){
        int k0 = kt * 32 + quad * 8;
        v8s av = *(const v8s*)&AT[rr][k0];
        v8s bv = *(const v8s*)&WT[jl][k0];
        acc = __builtin_amdgcn_mfma_f32_16x16x32_bf16(av, bv, acc, 0, 0, 0);
      }
      float bias = biasL[jl], w0 = w0L[jl];
      int gate = jl & 3;
      #pragma unroll
      for(int r = 0; r < 4; ++r){
        int bl = quad * 4 + r;
        float pre = acc[r] + bias + predfL[bl] * w0;
        gact[jl][bl] = (gate == 2) ? ftanh(pre) : fsig(pre);
      }
    }
    __syncthreads();
    if(tid < 256){
      int bl = tid >> 4, dl = tid & 15;
      float gi = gact[dl * 4 + 0][bl];
      float gf = gact[dl * 4 + 1][bl];
      float gg = gact[dl * 4 + 2][bl];
      float go = gact[dl * 4 + 3][bl];
      int bg = m16 + bl, dg = n * 16 + dl;
      float cn = gf * c_reg + gi * gg;
      c_reg = cn;
      float hn = go * ftanh(cn);
      st16_c(&xcatN[(size_t)bg * 512 + 256 + dg], (unsigned short)bf16r(hn));
      hl[bl][dl] = hn;
      float pp = hn * WoutL[dl];
      #pragma unroll
      for(int o = 8; o; o >>= 1) pp += __shfl_xor(pp, o, 64);
      if(dl == 0) stf_c(&predp[n * 256 + bg], pp);
    }
    __syncthreads();
    if(tid < 256){
      int bl = tid >> 4, ag = tid & 15;
      int bg = m16 + bl;
      float a0[8] = {0, 0, 0, 0, 0, 0, 0, 0};
      #pragma unroll
      for(int d = 0; d < 16; ++d){
        float hv = hl[bl][d];
        #pragma unroll
        for(int j = 0; j < 8; ++j) a0[j] += hv * WdecL[d][ag * 8 + j];
      }
      float* dst = &dpp[((size_t)bg * 16 + n) * 128 + ag * 8];
      #pragma unroll
      for(int j = 0; j < 4; ++j){
        uint64_t uu = (uint64_t)__float_as_uint(a0[2 * j]) |
                      ((uint64_t)__float_as_uint(a0[2 * j + 1]) << 32);
        st64_c((uint64_t*)(dst + 2 * j), uu);
      }
    }
    __syncthreads();                 // drains vmcnt: dpp/predp/h stores acked
    if(tid == 0) flag_st(&flagB[b], (unsigned)(t + 1));
  }

  // ---- finalize t=47 prediction ----
  if(tid < 16){
    while(flag_ld(&flagB[m16 + tid]) < 48u) __builtin_amdgcn_s_sleep(1);
  }
  __syncthreads();
  if(tid == 0){
    float pf = 0.f;
    #pragma unroll
    for(int nn = 0; nn < 16; ++nn) pf += ldf_c(&predp[nn * 256 + b]);
    out[b * 48 + 47] = pf + sB;
  }
}

extern "C" void kernel_launch(void* const* d_in, const int* in_sizes, int n_in,
                              void* d_out, int out_size, void* d_ws, size_t ws_size,
                              hipStream_t stream) {
  (void)in_sizes; (void)n_in; (void)out_size; (void)ws_size;
  const float* enc  = (const float*)d_in[0];
  const float* h0   = (const float*)d_in[1];
  const float* c0   = (const float*)d_in[2];
  const float* Wenc = (const float*)d_in[3];
  const float* Wdec = (const float*)d_in[4];
  const float* v    = (const float*)d_in[5];
  const float* Wih  = (const float*)d_in[6];
  const float* Whh  = (const float*)d_in[7];
  const float* bih  = (const float*)d_in[8];
  const float* bhh  = (const float*)d_in[9];
  const float* Wout = (const float*)d_in[10];
  const float* bout = (const float*)d_in[11];
  float* out = (float*)d_out;
  uint8_t* p = (uint8_t*)d_ws;

  uint32_t* encb = (uint32_t*)p;            p += 67108864ull;  // [256][512][128] u32 pairs
  unsigned short* ep = (unsigned short*)p;  p += 33554432ull;  // [256][128][512] bf16
  unsigned short* WmT = (unsigned short*)p; p += 1048576ull;   // [1024][512] bf16
  float* biasc  = (float*)p;                p += 4096ull;
  float* w0v    = (float*)p;                p += 4096ull;
  unsigned short* WencTh = (unsigned short*)p; p += 131072ull; // [128][256] bf16 hi
  unsigned short* WencTl = (unsigned short*)p; p += 131072ull; // [128][256] bf16 lo
  float* dpp    = (float*)p;                p += 2097152ull;   // [256][16][128] f32
  float* predp  = (float*)p;                p += 16384ull;     // [16][256] f32
  unsigned short* xcat2 = (unsigned short*)p; p += 524288ull;  // 2 x [256][512] bf16

  // flags/predf alias WencTh's space (dead after k_enc_proj; k_zero runs after it)
  unsigned* flagA = (unsigned*)WencTh;        // [256]
  unsigned* flagB = flagA + 256;              // [256]
  float*    predf = (float*)(flagA + 512);    // [256]

  k_pack<<<dim3(384), dim3(256), 0, stream>>>(Wih, Whh, bih, bhh, Wenc, WmT, biasc, w0v,
                                              WencTh, WencTl);
  k_enc_proj<<<dim3(1024), dim3(256), 0, stream>>>(enc, WencTh, WencTl, ep, encb);
  k_zero<<<dim3(1), dim3(512), 0, stream>>>(flagA);
  k_steps<<<dim3(256), dim3(512), 0, stream>>>(encb, ep, WmT, biasc, w0v, Wdec, Wout,
                                               h0, c0, v, bout, flagA, flagB, predf,
                                               dpp, predp, xcat2, out);
}